// Round 1
// baseline (21.941 us; speedup 1.0000x reference)
//
#include <hip/hip_runtime.h>

#define NBIN 50
#define DIM  64
#define KPT  4
#define TPB  256

// One block per batch row b. Build per-b bin table in LDS:
//   comb[bin][d] = W1[bin][d] + b1[d] + sum_j ego[b][j] * W1[52+j][d]
// laid out as [d4][bin] float4 (d4 = d/4) so the gather is one ds_read_b128
// per 4 feature dims. Uniform weights (W1 rows 50,51 and W2) load via
// wave-uniform pointers -> s_load (scalar cache), off the VALU/LDS pipes.
__global__ __launch_bounds__(TPB, 8) void scorer_kernel(
    const float* __restrict__ goal,   // (B, K, 2)
    const float* __restrict__ ego,    // (B, 4)
    const float* __restrict__ W1,     // (56, 64) row-major
    const float* __restrict__ b1,     // (64)
    const float* __restrict__ W2,     // (64, 1)
    const float* __restrict__ b2,     // (1)
    float* __restrict__ out,          // (B, K)
    int K)
{
    __shared__ float4 comb[16 * NBIN];   // [d4][bin], 12.8 KB
    __shared__ float  e_lds[DIM];

    const int b   = blockIdx.x;
    const int tid = threadIdx.x;

    // per-b ego/bias fold (uniform per block)
    const float4 eg = ((const float4*)ego)[b];
    if (tid < DIM) {
        float v = b1[tid]
                + eg.x * W1[52 * DIM + tid]
                + eg.y * W1[53 * DIM + tid]
                + eg.z * W1[54 * DIM + tid]
                + eg.w * W1[55 * DIM + tid];
        e_lds[tid] = v;
    }
    __syncthreads();

    // build comb table: i = bin*64 + d (coalesced W1 reads)
    for (int i = tid; i < NBIN * DIM; i += TPB) {
        int bin = i >> 6;
        int d   = i & 63;
        float v = W1[i] + e_lds[d];
        ((float*)comb)[(((d >> 2) * NBIN) + bin) * 4 + (d & 3)] = v;
    }
    __syncthreads();

    const float2* gp   = (const float2*)goal + (size_t)b * K;
    const float4* w50v = (const float4*)(W1 + 50 * DIM);
    const float4* w51v = (const float4*)(W1 + 51 * DIM);
    const float4* w2v  = (const float4*)W2;
    const float  bias2 = b2[0];

    float2 p[KPT];
    int    idx[KPT];
    float  acc[KPT];

#pragma unroll
    for (int j = 0; j < KPT; ++j) {
        int k = j * TPB + tid;
        p[j] = gp[k];
        // exact IEEE f32 replication of jax: floor((sqrt(x*x+y*y)/50)*50)
        float r2 = __fadd_rn(__fmul_rn(p[j].x, p[j].x), __fmul_rn(p[j].y, p[j].y));
        float r  = __fsqrt_rn(r2);
        float fv = floorf(__fmul_rn(__fdiv_rn(r, 50.0f), 50.0f));
        int ix = (int)fv;
        ix = ix < 0 ? 0 : (ix > NBIN - 1 ? NBIN - 1 : ix);
        idx[j] = ix;
        acc[j] = 0.0f;
    }

#pragma unroll
    for (int d4 = 0; d4 < 16; ++d4) {
        const float4 a  = w50v[d4];   // uniform -> s_load
        const float4 bb = w51v[d4];   // uniform -> s_load
        const float4 c  = w2v[d4];    // uniform -> s_load
#pragma unroll
        for (int j = 0; j < KPT; ++j) {
            const float4 g = comb[d4 * NBIN + idx[j]];  // ds_read_b128 gather
            float x = p[j].x, y = p[j].y;
            float t0 = fmaf(x, a.x, fmaf(y, bb.x, g.x));
            float t1 = fmaf(x, a.y, fmaf(y, bb.y, g.y));
            float t2 = fmaf(x, a.z, fmaf(y, bb.z, g.z));
            float t3 = fmaf(x, a.w, fmaf(y, bb.w, g.w));
            acc[j] = fmaf(c.x, fmaxf(t0, 0.0f), acc[j]);
            acc[j] = fmaf(c.y, fmaxf(t1, 0.0f), acc[j]);
            acc[j] = fmaf(c.z, fmaxf(t2, 0.0f), acc[j]);
            acc[j] = fmaf(c.w, fmaxf(t3, 0.0f), acc[j]);
        }
    }

    float* po = out + (size_t)b * K;
#pragma unroll
    for (int j = 0; j < KPT; ++j) {
        po[j * TPB + tid] = acc[j] + bias2;
    }
}

extern "C" void kernel_launch(void* const* d_in, const int* in_sizes, int n_in,
                              void* d_out, int out_size, void* d_ws, size_t ws_size,
                              hipStream_t stream) {
    const float* goal = (const float*)d_in[0];
    const float* ego  = (const float*)d_in[1];
    const float* W1   = (const float*)d_in[2];
    const float* b1   = (const float*)d_in[3];
    const float* W2   = (const float*)d_in[4];
    const float* b2   = (const float*)d_in[5];
    float* out = (float*)d_out;

    int B = in_sizes[1] / 4;          // ego_state is (B, 4)
    int K = in_sizes[0] / (2 * B);    // goal_positions is (B, K, 2)

    scorer_kernel<<<dim3(B), dim3(TPB), 0, stream>>>(goal, ego, W1, b1, W2, b2, out, K);
}